// Round 13
// baseline (359.229 us; speedup 1.0000x reference)
//
#include <hip/hip_runtime.h>
#include <hip/hip_bf16.h>

// ResnetBlockDDPMpp_Adagn: B=8, CIN=COUT=256, H=W=64, G=32, K=3
// Round 13 (on R12 pass, 267us):
//  - R12: 4x weight-traffic cut -> -3%. R10: 2x occupancy -> 0%. Per-CU cycle
//    accounting: MFMA 15 + VALU 24 + bankconf 13 = 52% -> ~50% is barrier/
//    latency stall from the per-tap lockstep [gather|barrier|MFMA] structure.
//  - Fix (deform only): register-direct A-fragments. Lane 16g+r gathers
//    px r, ch 8g..8g+7 (4 corner 16B loads + cvt) = its MFMA A-frag. NO LDS,
//    NO barriers, 0 bank conflicts; 9x8 k-loop is pure dataflow. Waves =
//    4 m-tiles x 2 n-halves (acc[8]); gather 2x redundant (not the limiter).

#define EPSV 1e-6f

typedef short  bf16x8 __attribute__((ext_vector_type(8)));
typedef float  f32x4  __attribute__((ext_vector_type(4)));

__device__ __forceinline__ float silu_f(float v){ return v / (1.f + __expf(-v)); }
__device__ __forceinline__ unsigned short f2bf(float f){
  unsigned int u = __float_as_uint(f);
  u = (u + 0x7FFFu + ((u >> 16) & 1u)) >> 16;
  return (unsigned short)u;
}
__device__ __forceinline__ float bf2f(unsigned short u){
  return __uint_as_float(((unsigned int)u) << 16);
}

// ---------------- ws layout (float units) ----------------
// sizes (floats): h0b 4194304 | h1b 4194304 | offt 884736 | wtd 294912
//                 wtc 294912 | owtb 36864 | st0 4096 | st1 4096 | tproj 2048
#define WS_H0B     0            // 8*4096*256 bf16 (reused as h2 bf16)
#define WS_H1B     4194304      // 8*4096*256 bf16
#define WS_OFFT    8388608      // 8*4096*27 fp32
#define WS_WTD     9273344      // dcn bf16 [9][32][256][8]
#define WS_WTC     9568256      // conv1 bf16 same
#define WS_OFFWTB  9863168      // offw bf16 [9][32][32][8]
#define WS_STYLE0  9900032
#define WS_STYLE1  9904128
#define WS_TPROJ   9908224
#define WS_MU0     9910272
#define WS_RS0     9910528
#define WS_MU1     9910784
#define WS_RS1     9911040
// end 9,911,296 floats = 39.6 MB

// ---------- prep: weight packs + tiny GEMMs ----------
__global__ __launch_bounds__(256) void prep_kernel(
    const float* __restrict__ zemb, const float* __restrict__ temb,
    const float* __restrict__ g0w, const float* __restrict__ g0b,
    const float* __restrict__ g1w, const float* __restrict__ g1b,
    const float* __restrict__ d0w, const float* __restrict__ d0b,
    const float* __restrict__ dcn_w, const float* __restrict__ c1w,
    const float* __restrict__ offw,
    unsigned short* __restrict__ wtd, unsigned short* __restrict__ wtc,
    unsigned short* __restrict__ offwtb,
    float* __restrict__ style0, float* __restrict__ style1, float* __restrict__ tproj)
{
  int blk = blockIdx.x, t = threadIdx.x;
  if (blk < 2304) {                       // dcn pack: e=((k*32+c8)*256+o)*8+j
    int e = blk*256 + t;
    int j = e & 7, o = (e >> 3) & 255, c8 = (e >> 11) & 31, k = e >> 16;
    wtd[e] = f2bf(dcn_w[((o*256 + c8*8 + j)*9) + k]);
  } else if (blk < 4608) {                // conv1 pack
    int e = (blk-2304)*256 + t;
    int j = e & 7, o = (e >> 3) & 255, c8 = (e >> 11) & 31, k = e >> 16;
    wtc[e] = f2bf(c1w[((o*256 + c8*8 + j)*9) + k]);
  } else if (blk < 4896) {                // offw pack: [9][32 c8][32 o][8 j], oc>=27 -> 0
    int e = (blk-4608)*256 + t;           // 73728 elems
    int j = e & 7, o = (e >> 3) & 31, c8 = (e >> 8) & 31, k = e >> 13;
    int c = c8*8 + j;
    offwtb[e] = (o < 27) ? f2bf(offw[((o*256 + c)*9) + k]) : (unsigned short)0;
  } else if (blk < 4912) {                // style0 = zemb @ g0w.T + g0b (8x512)
    int e = (blk-4896)*256 + t; int b = e >> 9, j = e & 511;
    float s = g0b[j];
    const float* z = zemb + b*256; const float* w = g0w + j*256;
    for (int i = 0; i < 256; ++i) s += z[i]*w[i];
    style0[e] = s;
  } else if (blk < 4928) {                // style1
    int e = (blk-4912)*256 + t; int b = e >> 9, j = e & 511;
    float s = g1b[j];
    const float* z = zemb + b*256; const float* w = g1w + j*256;
    for (int i = 0; i < 256; ++i) s += z[i]*w[i];
    style1[e] = s;
  } else {                                // tproj = silu(temb) @ d0w.T + d0b (8x256)
    int e = (blk-4928)*256 + t; int b = e >> 8, o = e & 255;
    float s = d0b[o];
    const float* tb = temb + b*512; const float* w = d0w + o*512;
    for (int i = 0; i < 512; ++i) s += silu_f(tb[i])*w[i];
    tproj[e] = s;
  }
}

// ---------- reductions ----------
__device__ __forceinline__ void block_reduce2(float& s, float& q){
  for (int off = 32; off > 0; off >>= 1) {
    s += __shfl_down(s, off, 64);
    q += __shfl_down(q, off, 64);
  }
  __shared__ float ss[4], qs[4];
  int wid = threadIdx.x >> 6, lane = threadIdx.x & 63;
  if (lane == 0) { ss[wid] = s; qs[wid] = q; }
  __syncthreads();
  if (threadIdx.x == 0) { s = ss[0]+ss[1]+ss[2]+ss[3]; q = qs[0]+qs[1]+qs[2]+qs[3]; }
}

__global__ __launch_bounds__(256) void gn0_stats_kernel(
    const float* __restrict__ x, float* __restrict__ mu, float* __restrict__ rs)
{
  int blk = blockIdx.x;  // b*32+g ; NCHW group = 32768 contiguous
  const float4* p4 = (const float4*)(x + (size_t)blk*32768);
  float s = 0.f, q = 0.f;
  for (int i = threadIdx.x; i < 8192; i += 256) {
    float4 v = p4[i];
    s += v.x+v.y+v.z+v.w;
    q += v.x*v.x + v.y*v.y + v.z*v.z + v.w*v.w;
  }
  block_reduce2(s, q);
  if (threadIdx.x == 0) {
    float m = s * (1.f/32768.f);
    float var = q * (1.f/32768.f) - m*m;
    mu[blk] = m; rs[blk] = rsqrtf(var + EPSV);
  }
}

// GN stats over h1b (bf16 NHWC)
__global__ __launch_bounds__(256) void gn1_stats_kernel(
    const unsigned short* __restrict__ h1b, float* __restrict__ mu, float* __restrict__ rs)
{
  int blk = blockIdx.x;  // b*32+g
  int b = blk >> 5, g = blk & 31;
  const unsigned short* base = h1b + (size_t)b*1048576 + g*8;
  float s = 0.f, q = 0.f;
  for (int px = threadIdx.x; px < 4096; px += 256) {
    bf16x8 v = *(const bf16x8*)(base + (size_t)px*256);
    #pragma unroll
    for (int e = 0; e < 8; ++e) {
      float f = bf2f((unsigned short)v[e]);
      s += f; q += f*f;
    }
  }
  block_reduce2(s, q);
  if (threadIdx.x == 0) {
    float m = s * (1.f/32768.f);
    float var = q * (1.f/32768.f) - m*m;
    mu[blk] = m; rs[blk] = rsqrtf(var + EPSV);
  }
}

// ---------- h0 = silu(adagn(x)) NCHW -> NHWC bf16 ----------
__global__ __launch_bounds__(256) void h0_kernel(
    const float* __restrict__ x, const float* __restrict__ style0,
    const float* __restrict__ mu, const float* __restrict__ rs,
    unsigned short* __restrict__ h0b)
{
  int blk = blockIdx.x;          // b(8) x ptile(64) x ctile(8)
  int b  = blk >> 9;
  int pt = (blk >> 3) & 63;
  int ct = blk & 7;
  __shared__ float tile[32][65];
  int p0 = pt*64, c0 = ct*32;
  int t = threadIdx.x;
  for (int it = 0; it < 8; ++it) {
    int c = c0 + it*4 + (t >> 6);
    int p = p0 + (t & 63);
    float v = x[((size_t)(b*256 + c))*4096 + p];
    int g = c >> 3;
    float m  = mu[b*32+g], r = rs[b*32+g];
    float ga = style0[b*512 + c], be = style0[b*512 + 256 + c];
    float u = ga * (v - m) * r + be;
    tile[c - c0][p - p0] = silu_f(u);
  }
  __syncthreads();
  for (int it = 0; it < 8; ++it) {
    int pp = it*8 + (t >> 5);
    int cc = t & 31;
    h0b[((size_t)(b*4096 + p0 + pp))*256 + c0 + cc] = f2bf(tile[cc][pp]);
  }
}

// ---------- offset conv MFMA: 32 px x 32 oc (27 used), K=2304 ----------
__global__ __launch_bounds__(256) void offset_mfma_kernel(
    const unsigned short* __restrict__ h0b, const unsigned short* __restrict__ wt,
    const float* __restrict__ off_b, float* __restrict__ off_t)
{
  int bid = blockIdx.x;
  int b  = bid & 7;                            // XCD swizzle
  int p0 = (bid >> 3) * 32;
  int y = p0 >> 6, xb = p0 & 63;
  int t = threadIdx.x;
  int lane = t & 63, wv = t >> 6;
  int r = lane & 15, g = lane >> 4;

  __shared__ unsigned short aw[3*34*264];      // rows y-1..y+1, px xb-1..xb+32

  const unsigned short* hbase = h0b + (size_t)b*1048576;
  for (int idx = t; idx < 3264; idx += 256) {
    int row = idx / 1088, rem = idx - row*1088;
    int px = rem >> 5, c8 = rem & 31;
    int yy = y + row - 1, xx = xb - 1 + px;
    bf16x8 v = {0,0,0,0,0,0,0,0};
    if (yy >= 0 && yy < 64 && xx >= 0 && xx < 64)
      v = *(const bf16x8*)&hbase[((size_t)yy*64 + xx)*256 + c8*8];
    *(bf16x8*)&aw[(row*34 + px)*264 + c8*8] = v;
  }
  __syncthreads();

  int m = wv & 1, n = wv >> 1;                 // wave -> (px half, oc half)
  f32x4 acc = {0.f,0.f,0.f,0.f};
  for (int k = 0; k < 9; ++k) {
    int ky = k/3, kxo = k%3;
    const unsigned short* abase = &aw[(ky*34)*264];
    const unsigned short* wk = wt + (size_t)k*8192;   // [32 c8][32 o][8]
    #pragma unroll
    for (int kc = 0; kc < 8; ++kc) {
      bf16x8 a = *(const bf16x8*)&abase[(kxo + m*16 + r)*264 + kc*32 + g*8];
      bf16x8 bf = *(const bf16x8*)&wk[(size_t)((kc*4 + g)*32 + n*16 + r)*8];
      acc = __builtin_amdgcn_mfma_f32_16x16x32_bf16(a, bf, acc, 0, 0, 0);
    }
  }

  int oc = n*16 + r;
  if (oc < 27) {
    float bs = off_b[oc];
    #pragma unroll
    for (int j = 0; j < 4; ++j) {
      int px = m*16 + g*4 + j;
      off_t[((size_t)(b*4096) + p0 + px)*27 + oc] = acc[j] + bs;
    }
  }
}

// ---------- deformable conv: register-direct A-frags, NO LDS, NO barriers ----------
__global__ __launch_bounds__(512, 2) void deform_mfma_kernel(
    const unsigned short* __restrict__ h0b, const float* __restrict__ off_t,
    const unsigned short* __restrict__ wt, const float* __restrict__ dcn_b,
    const float* __restrict__ tproj, unsigned short* __restrict__ h1b)
{
  int bid = blockIdx.x;
  int b  = bid & 7;                            // XCD swizzle (512 % 8 == 0)
  int p0 = (bid >> 3) * 64;                    // one full image row
  int y  = p0 >> 6;
  int t = threadIdx.x;                         // 0..511, 8 waves
  int lane = t & 63, wv = t >> 6;
  int r = lane & 15, g = lane >> 4;
  int mb = wv & 3, nh = wv >> 2;               // wave = (m-tile 16px, n-half 128out)

  int px = p0 + mb*16 + r;                     // this lane's A-row pixel
  int xq = px & 63;
  const unsigned short* hb = h0b + (size_t)b*1048576;
  const float* ob = off_t + ((size_t)(b*4096) + px)*27;

  f32x4 zero4 = {0.f,0.f,0.f,0.f};
  f32x4 acc[8];
  #pragma unroll
  for (int n = 0; n < 8; ++n) acc[n] = zero4;

  for (int k = 0; k < 9; ++k) {
    // lane-local tap params (4 g-lanes per px redundant; cheap VALU)
    float dy = ob[2*k], dx = ob[2*k+1];
    float mask = 1.f / (1.f + __expf(-ob[18+k]));
    float py  = dy + (float)(k/3 + y - 1);
    float pxf = dx + (float)(k%3 + xq - 1);
    float fy0 = floorf(py), fx0 = floorf(pxf);
    float wy1 = py - fy0, wx1 = pxf - fx0;
    int y0 = (int)fy0, x0 = (int)fx0, y1 = y0+1, x1 = x0+1;
    float vy0 = (y0 >= 0 && y0 < 64) ? 1.f : 0.f;
    float vy1 = (y1 >= 0 && y1 < 64) ? 1.f : 0.f;
    float vx0 = (x0 >= 0 && x0 < 64) ? 1.f : 0.f;
    float vx1 = (x1 >= 0 && x1 < 64) ? 1.f : 0.f;
    int iy0 = min(max(y0,0),63), ix0 = min(max(x0,0),63);
    int iy1 = min(max(y1,0),63), ix1 = min(max(x1,0),63);
    float w00 = (1.f-wy1)*(1.f-wx1)*vy0*vx0*mask;
    float w01 = (1.f-wy1)*wx1      *vy0*vx1*mask;
    float w10 = wy1      *(1.f-wx1)*vy1*vx0*mask;
    float w11 = wy1      *wx1      *vy1*vx1*mask;

    // corner base pointers at this lane's channel slice (8g), advance +32/kc
    const unsigned short* a00 = hb + ((size_t)iy0*64 + ix0)*256 + g*8;
    const unsigned short* a01 = hb + ((size_t)iy0*64 + ix1)*256 + g*8;
    const unsigned short* a10 = hb + ((size_t)iy1*64 + ix0)*256 + g*8;
    const unsigned short* a11 = hb + ((size_t)iy1*64 + ix1)*256 + g*8;

    const unsigned short* wk = wt + (size_t)k*65536 + (size_t)g*2048 + (nh*128 + r)*8;

    // prefetch kc=0 corners
    bf16x8 c00 = *(const bf16x8*)(a00);
    bf16x8 c01 = *(const bf16x8*)(a01);
    bf16x8 c10 = *(const bf16x8*)(a10);
    bf16x8 c11 = *(const bf16x8*)(a11);

    #pragma unroll
    for (int kc = 0; kc < 8; ++kc) {
      bf16x8 n00, n01, n10, n11;
      if (kc < 7) {                            // issue next-chunk loads early
        n00 = *(const bf16x8*)(a00 + (kc+1)*32);
        n01 = *(const bf16x8*)(a01 + (kc+1)*32);
        n10 = *(const bf16x8*)(a10 + (kc+1)*32);
        n11 = *(const bf16x8*)(a11 + (kc+1)*32);
      }
      bf16x8 af;
      #pragma unroll
      for (int e = 0; e < 8; ++e) {
        float v = w00*bf2f((unsigned short)c00[e])
                + w01*bf2f((unsigned short)c01[e])
                + w10*bf2f((unsigned short)c10[e])
                + w11*bf2f((unsigned short)c11[e]);
        af[e] = (short)f2bf(v);
      }
      const unsigned short* wb = wk + (size_t)kc*8192;  // (kc*4+g)*2048
      #pragma unroll
      for (int n = 0; n < 8; ++n) {
        bf16x8 bfr = *(const bf16x8*)(wb + n*128);
        acc[n] = __builtin_amdgcn_mfma_f32_16x16x32_bf16(af, bfr, acc[n], 0, 0, 0);
      }
      c00 = n00; c01 = n01; c10 = n10; c11 = n11;
    }
  }

  #pragma unroll
  for (int n = 0; n < 8; ++n) {
    int o = nh*128 + n*16 + r;
    float bs = dcn_b[o] + tproj[b*256 + o];
    #pragma unroll
    for (int j = 0; j < 4; ++j) {
      int pxc = p0 + mb*16 + g*4 + j;          // C row = 4g+j (m89 layout)
      h1b[((size_t)(b*4096) + pxc)*256 + o] = f2bf(acc[n][j] + bs);
    }
  }
}

// ---------- h2 = silu(adagn(h1b)) -> bf16 NHWC ----------
__global__ __launch_bounds__(256) void h2_bf16_kernel(
    const unsigned short* __restrict__ h1b, const float* __restrict__ style1,
    const float* __restrict__ mu, const float* __restrict__ rs,
    unsigned short* __restrict__ h2b)
{
  size_t i = ((size_t)blockIdx.x*256 + threadIdx.x)*8;
  bf16x8 v = *(const bf16x8*)(h1b + i);
  int b = (int)(i >> 20);
  int c0 = (int)(i & 255);
  int g = c0 >> 3;
  float m  = mu[b*32+g], rr = rs[b*32+g];
  bf16x8 o;
  #pragma unroll
  for (int j = 0; j < 8; ++j) {
    int c = c0 + j;
    float ga = style1[b*512 + c], be = style1[b*512 + 256 + c];
    float u = ga * (bf2f((unsigned short)v[j]) - m) * rr + be;
    o[j] = (short)f2bf(silu_f(u));
  }
  *(bf16x8*)(h2b + i) = o;
}

// ---------- conv1 3x3 MFMA + residual, M=64 row, 8 waves x 32-out ----------
__global__ __launch_bounds__(512, 2) void conv1_mfma_kernel(
    const unsigned short* __restrict__ h2b, const unsigned short* __restrict__ wt,
    const float* __restrict__ c1_b, const float* __restrict__ x,
    float* __restrict__ out)
{
  int bid = blockIdx.x;
  int b  = bid & 7;                            // XCD swizzle (512 % 8 == 0)
  int p0 = (bid >> 3) * 64;                    // one full image row
  int y = p0 >> 6;
  int t = threadIdx.x;                         // 0..511
  int lane = t & 63, wv = t >> 6;              // 8 waves
  int r = lane & 15, g = lane >> 4;

  __shared__ unsigned short aw[3*66*264];      // rows y-1..y+1, px -1..64 (102KB)

  const unsigned short* h2base = h2b + (size_t)b*1048576;
  for (int idx = t; idx < 6336; idx += 512) {  // 3 rows * 66 px * 32 chunks
    int row = idx / 2112, rem = idx - row*2112;
    int px = rem >> 5, c8 = rem & 31;
    int yy = y + row - 1, xx = px - 1;
    bf16x8 v = {0,0,0,0,0,0,0,0};
    if (yy >= 0 && yy < 64 && xx >= 0 && xx < 64)
      v = *(const bf16x8*)&h2base[((size_t)yy*64 + xx)*256 + c8*8];
    *(bf16x8*)&aw[(row*66 + px)*264 + c8*8] = v;
  }
  __syncthreads();

  f32x4 zero4 = {0.f,0.f,0.f,0.f};
  f32x4 acc[4][2];
  #pragma unroll
  for (int m = 0; m < 4; ++m) { acc[m][0] = zero4; acc[m][1] = zero4; }

  int o_base = wv*32 + r;                      // 8 waves x UNIQUE 32-out slice
  for (int k = 0; k < 9; ++k) {
    int ky = k/3, kxo = k%3;
    const unsigned short* abase = &aw[(ky*66)*264];
    const unsigned short* wk = wt + (size_t)k*65536;
    #pragma unroll
    for (int kc = 0; kc < 8; ++kc) {
      bf16x8 a0 = *(const bf16x8*)&abase[(kxo +      r)*264 + kc*32 + g*8];
      bf16x8 a1 = *(const bf16x8*)&abase[(kxo + 16 + r)*264 + kc*32 + g*8];
      bf16x8 a2 = *(const bf16x8*)&abase[(kxo + 32 + r)*264 + kc*32 + g*8];
      bf16x8 a3 = *(const bf16x8*)&abase[(kxo + 48 + r)*264 + kc*32 + g*8];
      const unsigned short* wb = wk + (size_t)(kc*4 + g)*2048 + o_base*8;
      bf16x8 b0 = *(const bf16x8*)&wb[  0*8];
      bf16x8 b1 = *(const bf16x8*)&wb[ 16*8];
      acc[0][0] = __builtin_amdgcn_mfma_f32_16x16x32_bf16(a0, b0, acc[0][0], 0, 0, 0);
      acc[0][1] = __builtin_amdgcn_mfma_f32_16x16x32_bf16(a0, b1, acc[0][1], 0, 0, 0);
      acc[1][0] = __builtin_amdgcn_mfma_f32_16x16x32_bf16(a1, b0, acc[1][0], 0, 0, 0);
      acc[1][1] = __builtin_amdgcn_mfma_f32_16x16x32_bf16(a1, b1, acc[1][1], 0, 0, 0);
      acc[2][0] = __builtin_amdgcn_mfma_f32_16x16x32_bf16(a2, b0, acc[2][0], 0, 0, 0);
      acc[2][1] = __builtin_amdgcn_mfma_f32_16x16x32_bf16(a2, b1, acc[2][1], 0, 0, 0);
      acc[3][0] = __builtin_amdgcn_mfma_f32_16x16x32_bf16(a3, b0, acc[3][0], 0, 0, 0);
      acc[3][1] = __builtin_amdgcn_mfma_f32_16x16x32_bf16(a3, b1, acc[3][1], 0, 0, 0);
    }
  }

  #pragma unroll
  for (int nn = 0; nn < 2; ++nn) {
    int o = o_base + nn*16;
    float cb = c1_b[o];
    #pragma unroll
    for (int m = 0; m < 4; ++m)
      #pragma unroll
      for (int j = 0; j < 4; ++j) {
        int pxl = m*16 + g*4 + j;
        size_t oi = ((size_t)(b*256 + o))*4096 + p0 + pxl;
        out[oi] = x[oi] + acc[m][nn][j] + cb;
      }
  }
}

extern "C" void kernel_launch(void* const* d_in, const int* in_sizes, int n_in,
                              void* d_out, int out_size, void* d_ws, size_t ws_size,
                              hipStream_t stream) {
  const float* x    = (const float*)d_in[0];
  const float* temb = (const float*)d_in[1];
  const float* zemb = (const float*)d_in[2];
  const float* g0w  = (const float*)d_in[3];
  const float* g0b  = (const float*)d_in[4];
  const float* offw = (const float*)d_in[5];
  const float* offb = (const float*)d_in[6];
  const float* dcnw = (const float*)d_in[7];
  const float* dcnb = (const float*)d_in[8];
  const float* d0w  = (const float*)d_in[9];
  const float* d0b  = (const float*)d_in[10];
  const float* g1w  = (const float*)d_in[11];
  const float* g1b  = (const float*)d_in[12];
  const float* c1w  = (const float*)d_in[13];
  const float* c1b  = (const float*)d_in[14];
  float* out = (float*)d_out;
  float* ws  = (float*)d_ws;

  unsigned short* h0b = (unsigned short*)(ws + WS_H0B);
  unsigned short* h1b = (unsigned short*)(ws + WS_H1B);
  float* off_t   = ws + WS_OFFT;
  unsigned short* wtd  = (unsigned short*)(ws + WS_WTD);
  unsigned short* wtc  = (unsigned short*)(ws + WS_WTC);
  unsigned short* owtb = (unsigned short*)(ws + WS_OFFWTB);
  float* style0  = ws + WS_STYLE0;
  float* style1  = ws + WS_STYLE1;
  float* tproj   = ws + WS_TPROJ;
  float* mu0     = ws + WS_MU0;
  float* rs0     = ws + WS_RS0;
  float* mu1     = ws + WS_MU1;
  float* rs1     = ws + WS_RS1;
  unsigned short* h2b = (unsigned short*)(ws + WS_H0B);  // reuse (h0 dead after deform)

  prep_kernel<<<4936, 256, 0, stream>>>(zemb, temb, g0w, g0b, g1w, g1b, d0w, d0b,
                                        dcnw, c1w, offw, wtd, wtc, owtb,
                                        style0, style1, tproj);
  gn0_stats_kernel<<<256, 256, 0, stream>>>(x, mu0, rs0);
  h0_kernel<<<4096, 256, 0, stream>>>(x, style0, mu0, rs0, h0b);
  offset_mfma_kernel<<<1024, 256, 0, stream>>>(h0b, owtb, offb, off_t);
  deform_mfma_kernel<<<512, 512, 0, stream>>>(h0b, off_t, wtd, dcnb, tproj, h1b);
  gn1_stats_kernel<<<256, 256, 0, stream>>>(h1b, mu1, rs1);
  h2_bf16_kernel<<<4096, 256, 0, stream>>>(h1b, style1, mu1, rs1, h2b);
  conv1_mfma_kernel<<<512, 512, 0, stream>>>(h2b, wtc, c1b, x, out);
}

// Round 14
// 270.678 us; speedup vs baseline: 1.3271x; 1.3271x over previous
//
#include <hip/hip_runtime.h>
#include <hip/hip_bf16.h>

// ResnetBlockDDPMpp_Adagn: B=8, CIN=COUT=256, H=W=64, G=32, K=3
// Round 14 (on R13 FAIL 359us -> revert deform to R12 form, 267us baseline):
//  - R13 lesson: no-LDS gather = 4x worse coalescing (16x64B vs 8x512B per
//    instr) -> 2x slower. LDS staging stays.
//  - R12 ledger: VALU 24% + MFMA 15% serialized by per-tap barrier with only
//    ONE resident block (86KB LDS). Fix: pack tap tables (idx->int, w->float4)
//    -> 79.1KB -> 2 blocks/CU -> block A's gather overlaps block B's MFMA.
//  - conv1 now reads h1b and applies adagn+silu during staging (h2 kernel
//    and its 16MB round-trip eliminated).

#define EPSV 1e-6f

typedef short  bf16x8 __attribute__((ext_vector_type(8)));
typedef float  f32x4  __attribute__((ext_vector_type(4)));

__device__ __forceinline__ float silu_f(float v){ return v / (1.f + __expf(-v)); }
__device__ __forceinline__ unsigned short f2bf(float f){
  unsigned int u = __float_as_uint(f);
  u = (u + 0x7FFFu + ((u >> 16) & 1u)) >> 16;
  return (unsigned short)u;
}
__device__ __forceinline__ float bf2f(unsigned short u){
  return __uint_as_float(((unsigned int)u) << 16);
}

// ---------------- ws layout (float units) ----------------
// sizes (floats): h0b 4194304 | h1b 4194304 | offt 884736 | wtd 294912
//                 wtc 294912 | owtb 36864 | st0 4096 | st1 4096 | tproj 2048
#define WS_H0B     0            // 8*4096*256 bf16
#define WS_H1B     4194304      // 8*4096*256 bf16
#define WS_OFFT    8388608      // 8*4096*27 fp32
#define WS_WTD     9273344      // dcn bf16 [9][32][256][8]
#define WS_WTC     9568256      // conv1 bf16 same
#define WS_OFFWTB  9863168      // offw bf16 [9][32][32][8]
#define WS_STYLE0  9900032
#define WS_STYLE1  9904128
#define WS_TPROJ   9908224
#define WS_MU0     9910272
#define WS_RS0     9910528
#define WS_MU1     9910784
#define WS_RS1     9911040
// end 9,911,296 floats = 39.6 MB

// ---------- prep: weight packs + tiny GEMMs ----------
__global__ __launch_bounds__(256) void prep_kernel(
    const float* __restrict__ zemb, const float* __restrict__ temb,
    const float* __restrict__ g0w, const float* __restrict__ g0b,
    const float* __restrict__ g1w, const float* __restrict__ g1b,
    const float* __restrict__ d0w, const float* __restrict__ d0b,
    const float* __restrict__ dcn_w, const float* __restrict__ c1w,
    const float* __restrict__ offw,
    unsigned short* __restrict__ wtd, unsigned short* __restrict__ wtc,
    unsigned short* __restrict__ offwtb,
    float* __restrict__ style0, float* __restrict__ style1, float* __restrict__ tproj)
{
  int blk = blockIdx.x, t = threadIdx.x;
  if (blk < 2304) {                       // dcn pack: e=((k*32+c8)*256+o)*8+j
    int e = blk*256 + t;
    int j = e & 7, o = (e >> 3) & 255, c8 = (e >> 11) & 31, k = e >> 16;
    wtd[e] = f2bf(dcn_w[((o*256 + c8*8 + j)*9) + k]);
  } else if (blk < 4608) {                // conv1 pack
    int e = (blk-2304)*256 + t;
    int j = e & 7, o = (e >> 3) & 255, c8 = (e >> 11) & 31, k = e >> 16;
    wtc[e] = f2bf(c1w[((o*256 + c8*8 + j)*9) + k]);
  } else if (blk < 4896) {                // offw pack: [9][32 c8][32 o][8 j], oc>=27 -> 0
    int e = (blk-4608)*256 + t;           // 73728 elems
    int j = e & 7, o = (e >> 3) & 31, c8 = (e >> 8) & 31, k = e >> 13;
    int c = c8*8 + j;
    offwtb[e] = (o < 27) ? f2bf(offw[((o*256 + c)*9) + k]) : (unsigned short)0;
  } else if (blk < 4912) {                // style0 = zemb @ g0w.T + g0b (8x512)
    int e = (blk-4896)*256 + t; int b = e >> 9, j = e & 511;
    float s = g0b[j];
    const float* z = zemb + b*256; const float* w = g0w + j*256;
    for (int i = 0; i < 256; ++i) s += z[i]*w[i];
    style0[e] = s;
  } else if (blk < 4928) {                // style1
    int e = (blk-4912)*256 + t; int b = e >> 9, j = e & 511;
    float s = g1b[j];
    const float* z = zemb + b*256; const float* w = g1w + j*256;
    for (int i = 0; i < 256; ++i) s += z[i]*w[i];
    style1[e] = s;
  } else {                                // tproj = silu(temb) @ d0w.T + d0b (8x256)
    int e = (blk-4928)*256 + t; int b = e >> 8, o = e & 255;
    float s = d0b[o];
    const float* tb = temb + b*512; const float* w = d0w + o*512;
    for (int i = 0; i < 512; ++i) s += silu_f(tb[i])*w[i];
    tproj[e] = s;
  }
}

// ---------- reductions ----------
__device__ __forceinline__ void block_reduce2(float& s, float& q){
  for (int off = 32; off > 0; off >>= 1) {
    s += __shfl_down(s, off, 64);
    q += __shfl_down(q, off, 64);
  }
  __shared__ float ss[4], qs[4];
  int wid = threadIdx.x >> 6, lane = threadIdx.x & 63;
  if (lane == 0) { ss[wid] = s; qs[wid] = q; }
  __syncthreads();
  if (threadIdx.x == 0) { s = ss[0]+ss[1]+ss[2]+ss[3]; q = qs[0]+qs[1]+qs[2]+qs[3]; }
}

__global__ __launch_bounds__(256) void gn0_stats_kernel(
    const float* __restrict__ x, float* __restrict__ mu, float* __restrict__ rs)
{
  int blk = blockIdx.x;  // b*32+g ; NCHW group = 32768 contiguous
  const float4* p4 = (const float4*)(x + (size_t)blk*32768);
  float s = 0.f, q = 0.f;
  for (int i = threadIdx.x; i < 8192; i += 256) {
    float4 v = p4[i];
    s += v.x+v.y+v.z+v.w;
    q += v.x*v.x + v.y*v.y + v.z*v.z + v.w*v.w;
  }
  block_reduce2(s, q);
  if (threadIdx.x == 0) {
    float m = s * (1.f/32768.f);
    float var = q * (1.f/32768.f) - m*m;
    mu[blk] = m; rs[blk] = rsqrtf(var + EPSV);
  }
}

// GN stats over h1b (bf16 NHWC)
__global__ __launch_bounds__(256) void gn1_stats_kernel(
    const unsigned short* __restrict__ h1b, float* __restrict__ mu, float* __restrict__ rs)
{
  int blk = blockIdx.x;  // b*32+g
  int b = blk >> 5, g = blk & 31;
  const unsigned short* base = h1b + (size_t)b*1048576 + g*8;
  float s = 0.f, q = 0.f;
  for (int px = threadIdx.x; px < 4096; px += 256) {
    bf16x8 v = *(const bf16x8*)(base + (size_t)px*256);
    #pragma unroll
    for (int e = 0; e < 8; ++e) {
      float f = bf2f((unsigned short)v[e]);
      s += f; q += f*f;
    }
  }
  block_reduce2(s, q);
  if (threadIdx.x == 0) {
    float m = s * (1.f/32768.f);
    float var = q * (1.f/32768.f) - m*m;
    mu[blk] = m; rs[blk] = rsqrtf(var + EPSV);
  }
}

// ---------- h0 = silu(adagn(x)) NCHW -> NHWC bf16 ----------
__global__ __launch_bounds__(256) void h0_kernel(
    const float* __restrict__ x, const float* __restrict__ style0,
    const float* __restrict__ mu, const float* __restrict__ rs,
    unsigned short* __restrict__ h0b)
{
  int blk = blockIdx.x;          // b(8) x ptile(64) x ctile(8)
  int b  = blk >> 9;
  int pt = (blk >> 3) & 63;
  int ct = blk & 7;
  __shared__ float tile[32][65];
  int p0 = pt*64, c0 = ct*32;
  int t = threadIdx.x;
  for (int it = 0; it < 8; ++it) {
    int c = c0 + it*4 + (t >> 6);
    int p = p0 + (t & 63);
    float v = x[((size_t)(b*256 + c))*4096 + p];
    int g = c >> 3;
    float m  = mu[b*32+g], r = rs[b*32+g];
    float ga = style0[b*512 + c], be = style0[b*512 + 256 + c];
    float u = ga * (v - m) * r + be;
    tile[c - c0][p - p0] = silu_f(u);
  }
  __syncthreads();
  for (int it = 0; it < 8; ++it) {
    int pp = it*8 + (t >> 5);
    int cc = t & 31;
    h0b[((size_t)(b*4096 + p0 + pp))*256 + c0 + cc] = f2bf(tile[cc][pp]);
  }
}

// ---------- offset conv MFMA: 32 px x 32 oc (27 used), K=2304 ----------
__global__ __launch_bounds__(256) void offset_mfma_kernel(
    const unsigned short* __restrict__ h0b, const unsigned short* __restrict__ wt,
    const float* __restrict__ off_b, float* __restrict__ off_t)
{
  int bid = blockIdx.x;
  int b  = bid & 7;                            // XCD swizzle
  int p0 = (bid >> 3) * 32;
  int y = p0 >> 6, xb = p0 & 63;
  int t = threadIdx.x;
  int lane = t & 63, wv = t >> 6;
  int r = lane & 15, g = lane >> 4;

  __shared__ unsigned short aw[3*34*264];      // rows y-1..y+1, px xb-1..xb+32

  const unsigned short* hbase = h0b + (size_t)b*1048576;
  for (int idx = t; idx < 3264; idx += 256) {
    int row = idx / 1088, rem = idx - row*1088;
    int px = rem >> 5, c8 = rem & 31;
    int yy = y + row - 1, xx = xb - 1 + px;
    bf16x8 v = {0,0,0,0,0,0,0,0};
    if (yy >= 0 && yy < 64 && xx >= 0 && xx < 64)
      v = *(const bf16x8*)&hbase[((size_t)yy*64 + xx)*256 + c8*8];
    *(bf16x8*)&aw[(row*34 + px)*264 + c8*8] = v;
  }
  __syncthreads();

  int m = wv & 1, n = wv >> 1;                 // wave -> (px half, oc half)
  f32x4 acc = {0.f,0.f,0.f,0.f};
  for (int k = 0; k < 9; ++k) {
    int ky = k/3, kxo = k%3;
    const unsigned short* abase = &aw[(ky*34)*264];
    const unsigned short* wk = wt + (size_t)k*8192;   // [32 c8][32 o][8]
    #pragma unroll
    for (int kc = 0; kc < 8; ++kc) {
      bf16x8 a = *(const bf16x8*)&abase[(kxo + m*16 + r)*264 + kc*32 + g*8];
      bf16x8 bf = *(const bf16x8*)&wk[(size_t)((kc*4 + g)*32 + n*16 + r)*8];
      acc = __builtin_amdgcn_mfma_f32_16x16x32_bf16(a, bf, acc, 0, 0, 0);
    }
  }

  int oc = n*16 + r;
  if (oc < 27) {
    float bs = off_b[oc];
    #pragma unroll
    for (int j = 0; j < 4; ++j) {
      int px = m*16 + g*4 + j;
      off_t[((size_t)(b*4096) + p0 + px)*27 + oc] = acc[j] + bs;
    }
  }
}

// ---------- deformable conv: R12 structure, packed tables -> 2 blocks/CU ----------
__global__ __launch_bounds__(512, 2) void deform_mfma_kernel(
    const unsigned short* __restrict__ h0b, const float* __restrict__ off_t,
    const unsigned short* __restrict__ wt, const float* __restrict__ dcn_b,
    const float* __restrict__ tproj, unsigned short* __restrict__ h1b)
{
  int bid = blockIdx.x;
  int b  = bid & 7;                            // XCD swizzle (512 % 8 == 0)
  int p0 = (bid >> 3) * 64;                    // one full image row
  int t = threadIdx.x;                         // 0..511
  int lane = t & 63, wv = t >> 6;              // 8 waves
  int r = lane & 15, g = lane >> 4;

  __shared__ unsigned short samp[2][64*264];   // dbuf [px][264] bf16 (67.6KB)
  __shared__ int    pki[576];                  // packed iy0|ix0|iy1|ix1 (2.3KB)
  __shared__ float4 pkw[576];                  // w00..w11 (9.2KB) -> total 79.1KB

  for (int tp = t; tp < 576; tp += 512) {      // 64 px x 9 taps
    int i = tp / 9, k = tp - i*9;
    int p = p0 + i; int y = p >> 6, xq = p & 63;
    const float* ob = off_t + ((size_t)(b*4096) + p)*27;
    float dy = ob[2*k], dx = ob[2*k+1];
    float mask = 1.f / (1.f + __expf(-ob[18+k]));
    float py = dy + (float)(k/3 + y - 1);
    float px = dx + (float)(k%3 + xq - 1);
    float fy0 = floorf(py), fx0 = floorf(px);
    float wy1 = py - fy0, wx1 = px - fx0;
    int y0 = (int)fy0, x0 = (int)fx0, y1 = y0+1, x1 = x0+1;
    float vy0 = (y0 >= 0 && y0 < 64) ? 1.f : 0.f;
    float vy1 = (y1 >= 0 && y1 < 64) ? 1.f : 0.f;
    float vx0 = (x0 >= 0 && x0 < 64) ? 1.f : 0.f;
    float vx1 = (x1 >= 0 && x1 < 64) ? 1.f : 0.f;
    int iy0 = min(max(y0,0),63), ix0 = min(max(x0,0),63);
    int iy1 = min(max(y1,0),63), ix1 = min(max(x1,0),63);
    pki[tp] = iy0 | (ix0 << 8) | (iy1 << 16) | (ix1 << 24);
    float4 w;
    w.x = (1.f-wy1)*(1.f-wx1)*vy0*vx0*mask;
    w.y = (1.f-wy1)*wx1      *vy0*vx1*mask;
    w.z = wy1      *(1.f-wx1)*vy1*vx0*mask;
    w.w = wy1      *wx1      *vy1*vx1*mask;
    pkw[tp] = w;
  }
  __syncthreads();

  f32x4 zero4 = {0.f,0.f,0.f,0.f};
  f32x4 acc[4][2];
  #pragma unroll
  for (int m = 0; m < 4; ++m) { acc[m][0] = zero4; acc[m][1] = zero4; }

  const unsigned short* hb = h0b + (size_t)b*1048576;
  int px = t >> 3;                             // 8 threads per pixel (64 px)
  int ci = (t & 7) * 32;                       // 32 contiguous channels each
  int o_base = wv*32 + r;                      // 8 waves x UNIQUE 32-out slice

  bf16x8 pre[16];                              // 4 corners x 32ch
  auto loadk = [&](int kk) {
    int tp = px*9 + kk;
    int pk = pki[tp];
    int iy0 = pk & 255, ix0 = (pk >> 8) & 255, iy1 = (pk >> 16) & 255, ix1 = (pk >> 24) & 255;
    const bf16x8* q00 = (const bf16x8*)(hb + ((size_t)iy0*64 + ix0)*256 + ci);
    const bf16x8* q01 = (const bf16x8*)(hb + ((size_t)iy0*64 + ix1)*256 + ci);
    const bf16x8* q10 = (const bf16x8*)(hb + ((size_t)iy1*64 + ix0)*256 + ci);
    const bf16x8* q11 = (const bf16x8*)(hb + ((size_t)iy1*64 + ix1)*256 + ci);
    pre[0] = q00[0]; pre[1] = q00[1]; pre[2] = q00[2]; pre[3] = q00[3];
    pre[4] = q01[0]; pre[5] = q01[1]; pre[6] = q01[2]; pre[7] = q01[3];
    pre[8] = q10[0]; pre[9] = q10[1]; pre[10] = q10[2]; pre[11] = q10[3];
    pre[12] = q11[0]; pre[13] = q11[1]; pre[14] = q11[2]; pre[15] = q11[3];
  };

  loadk(0);
  for (int k = 0; k < 9; ++k) {
    { // cvt + weighted sum from prefetch regs -> LDS buf k&1
      int tp = px*9 + k;
      float4 w = pkw[tp];
      unsigned short* sp = &samp[k & 1][px*264 + ci];
      #pragma unroll
      for (int ch = 0; ch < 4; ++ch) {
        bf16x8 o;
        #pragma unroll
        for (int e = 0; e < 8; ++e) {
          float v = w.x*bf2f((unsigned short)pre[ch][e])
                  + w.y*bf2f((unsigned short)pre[4+ch][e])
                  + w.z*bf2f((unsigned short)pre[8+ch][e])
                  + w.w*bf2f((unsigned short)pre[12+ch][e]);
          o[e] = (short)f2bf(v);
        }
        *(bf16x8*)(sp + ch*8) = o;
      }
    }
    if (k < 8) loadk(k+1);                     // next-tap loads hide under MFMA
    __syncthreads();                           // ONE barrier per tap (dbuf)

    const unsigned short* sb = samp[k & 1];
    const unsigned short* wk = wt + (size_t)k*65536;   // [32][256][8] this tap
    #pragma unroll
    for (int kc = 0; kc < 8; ++kc) {
      bf16x8 a0 = *(const bf16x8*)&sb[(     r)*264 + kc*32 + g*8];
      bf16x8 a1 = *(const bf16x8*)&sb[(16 + r)*264 + kc*32 + g*8];
      bf16x8 a2 = *(const bf16x8*)&sb[(32 + r)*264 + kc*32 + g*8];
      bf16x8 a3 = *(const bf16x8*)&sb[(48 + r)*264 + kc*32 + g*8];
      const unsigned short* wb = wk + (size_t)(kc*4 + g)*2048 + o_base*8;
      bf16x8 b0 = *(const bf16x8*)&wb[  0*8];
      bf16x8 b1 = *(const bf16x8*)&wb[ 16*8];
      acc[0][0] = __builtin_amdgcn_mfma_f32_16x16x32_bf16(a0, b0, acc[0][0], 0, 0, 0);
      acc[0][1] = __builtin_amdgcn_mfma_f32_16x16x32_bf16(a0, b1, acc[0][1], 0, 0, 0);
      acc[1][0] = __builtin_amdgcn_mfma_f32_16x16x32_bf16(a1, b0, acc[1][0], 0, 0, 0);
      acc[1][1] = __builtin_amdgcn_mfma_f32_16x16x32_bf16(a1, b1, acc[1][1], 0, 0, 0);
      acc[2][0] = __builtin_amdgcn_mfma_f32_16x16x32_bf16(a2, b0, acc[2][0], 0, 0, 0);
      acc[2][1] = __builtin_amdgcn_mfma_f32_16x16x32_bf16(a2, b1, acc[2][1], 0, 0, 0);
      acc[3][0] = __builtin_amdgcn_mfma_f32_16x16x32_bf16(a3, b0, acc[3][0], 0, 0, 0);
      acc[3][1] = __builtin_amdgcn_mfma_f32_16x16x32_bf16(a3, b1, acc[3][1], 0, 0, 0);
    }
    // no second barrier: next tap writes the other buffer
  }

  #pragma unroll
  for (int nn = 0; nn < 2; ++nn) {
    int o = o_base + nn*16;
    float bs = dcn_b[o] + tproj[b*256 + o];
    #pragma unroll
    for (int m = 0; m < 4; ++m)
      #pragma unroll
      for (int j = 0; j < 4; ++j) {
        int pxl = m*16 + g*4 + j;
        h1b[((size_t)(b*4096) + pxl + p0)*256 + o] = f2bf(acc[m][nn][j] + bs);
      }
  }
}

// ---------- conv1 3x3 MFMA + residual, adagn+silu fused into staging ----------
__global__ __launch_bounds__(512, 2) void conv1_mfma_kernel(
    const unsigned short* __restrict__ h1b, const float* __restrict__ style1,
    const float* __restrict__ mu, const float* __restrict__ rs,
    const unsigned short* __restrict__ wt,
    const float* __restrict__ c1_b, const float* __restrict__ x,
    float* __restrict__ out)
{
  int bid = blockIdx.x;
  int b  = bid & 7;                            // XCD swizzle (512 % 8 == 0)
  int p0 = (bid >> 3) * 64;                    // one full image row
  int y = p0 >> 6;
  int t = threadIdx.x;                         // 0..511
  int lane = t & 63, wv = t >> 6;              // 8 waves
  int r = lane & 15, g = lane >> 4;

  __shared__ unsigned short aw[3*66*264];      // rows y-1..y+1, px -1..64 (102KB)

  const unsigned short* h1base = h1b + (size_t)b*1048576;
  for (int idx = t; idx < 6336; idx += 512) {  // 3 rows * 66 px * 32 chunks(8c)
    int row = idx / 2112, rem = idx - row*2112;
    int px = rem >> 5, c8 = rem & 31;
    int yy = y + row - 1, xx = px - 1;
    bf16x8 v = {0,0,0,0,0,0,0,0};
    if (yy >= 0 && yy < 64 && xx >= 0 && xx < 64) {
      bf16x8 h = *(const bf16x8*)&h1base[((size_t)yy*64 + xx)*256 + c8*8];
      int gg = c8;                             // group = c8 (8 ch per group)
      float m  = mu[b*32+gg], rr = rs[b*32+gg];
      #pragma unroll
      for (int j = 0; j < 8; ++j) {
        int c = c8*8 + j;
        float ga = style1[b*512 + c], be = style1[b*512 + 256 + c];
        float u = ga * (bf2f((unsigned short)h[j]) - m) * rr + be;
        v[j] = (short)f2bf(silu_f(u));
      }
    }
    *(bf16x8*)&aw[(row*66 + px)*264 + c8*8] = v;
  }
  __syncthreads();

  f32x4 zero4 = {0.f,0.f,0.f,0.f};
  f32x4 acc[4][2];
  #pragma unroll
  for (int m = 0; m < 4; ++m) { acc[m][0] = zero4; acc[m][1] = zero4; }

  int o_base = wv*32 + r;                      // 8 waves x UNIQUE 32-out slice
  for (int k = 0; k < 9; ++k) {
    int ky = k/3, kxo = k%3;
    const unsigned short* abase = &aw[(ky*66)*264];
    const unsigned short* wk = wt + (size_t)k*65536;
    #pragma unroll
    for (int kc = 0; kc < 8; ++kc) {
      bf16x8 a0 = *(const bf16x8*)&abase[(kxo +      r)*264 + kc*32 + g*8];
      bf16x8 a1 = *(const bf16x8*)&abase[(kxo + 16 + r)*264 + kc*32 + g*8];
      bf16x8 a2 = *(const bf16x8*)&abase[(kxo + 32 + r)*264 + kc*32 + g*8];
      bf16x8 a3 = *(const bf16x8*)&abase[(kxo + 48 + r)*264 + kc*32 + g*8];
      const unsigned short* wb = wk + (size_t)(kc*4 + g)*2048 + o_base*8;
      bf16x8 b0 = *(const bf16x8*)&wb[  0*8];
      bf16x8 b1 = *(const bf16x8*)&wb[ 16*8];
      acc[0][0] = __builtin_amdgcn_mfma_f32_16x16x32_bf16(a0, b0, acc[0][0], 0, 0, 0);
      acc[0][1] = __builtin_amdgcn_mfma_f32_16x16x32_bf16(a0, b1, acc[0][1], 0, 0, 0);
      acc[1][0] = __builtin_amdgcn_mfma_f32_16x16x32_bf16(a1, b0, acc[1][0], 0, 0, 0);
      acc[1][1] = __builtin_amdgcn_mfma_f32_16x16x32_bf16(a1, b1, acc[1][1], 0, 0, 0);
      acc[2][0] = __builtin_amdgcn_mfma_f32_16x16x32_bf16(a2, b0, acc[2][0], 0, 0, 0);
      acc[2][1] = __builtin_amdgcn_mfma_f32_16x16x32_bf16(a2, b1, acc[2][1], 0, 0, 0);
      acc[3][0] = __builtin_amdgcn_mfma_f32_16x16x32_bf16(a3, b0, acc[3][0], 0, 0, 0);
      acc[3][1] = __builtin_amdgcn_mfma_f32_16x16x32_bf16(a3, b1, acc[3][1], 0, 0, 0);
    }
  }

  #pragma unroll
  for (int nn = 0; nn < 2; ++nn) {
    int o = o_base + nn*16;
    float cb = c1_b[o];
    #pragma unroll
    for (int m = 0; m < 4; ++m)
      #pragma unroll
      for (int j = 0; j < 4; ++j) {
        int pxl = m*16 + g*4 + j;
        size_t oi = ((size_t)(b*256 + o))*4096 + p0 + pxl;
        out[oi] = x[oi] + acc[m][nn][j] + cb;
      }
  }
}

extern "C" void kernel_launch(void* const* d_in, const int* in_sizes, int n_in,
                              void* d_out, int out_size, void* d_ws, size_t ws_size,
                              hipStream_t stream) {
  const float* x    = (const float*)d_in[0];
  const float* temb = (const float*)d_in[1];
  const float* zemb = (const float*)d_in[2];
  const float* g0w  = (const float*)d_in[3];
  const float* g0b  = (const float*)d_in[4];
  const float* offw = (const float*)d_in[5];
  const float* offb = (const float*)d_in[6];
  const float* dcnw = (const float*)d_in[7];
  const float* dcnb = (const float*)d_in[8];
  const float* d0w  = (const float*)d_in[9];
  const float* d0b  = (const float*)d_in[10];
  const float* g1w  = (const float*)d_in[11];
  const float* g1b  = (const float*)d_in[12];
  const float* c1w  = (const float*)d_in[13];
  const float* c1b  = (const float*)d_in[14];
  float* out = (float*)d_out;
  float* ws  = (float*)d_ws;

  unsigned short* h0b = (unsigned short*)(ws + WS_H0B);
  unsigned short* h1b = (unsigned short*)(ws + WS_H1B);
  float* off_t   = ws + WS_OFFT;
  unsigned short* wtd  = (unsigned short*)(ws + WS_WTD);
  unsigned short* wtc  = (unsigned short*)(ws + WS_WTC);
  unsigned short* owtb = (unsigned short*)(ws + WS_OFFWTB);
  float* style0  = ws + WS_STYLE0;
  float* style1  = ws + WS_STYLE1;
  float* tproj   = ws + WS_TPROJ;
  float* mu0     = ws + WS_MU0;
  float* rs0     = ws + WS_RS0;
  float* mu1     = ws + WS_MU1;
  float* rs1     = ws + WS_RS1;

  prep_kernel<<<4936, 256, 0, stream>>>(zemb, temb, g0w, g0b, g1w, g1b, d0w, d0b,
                                        dcnw, c1w, offw, wtd, wtc, owtb,
                                        style0, style1, tproj);
  gn0_stats_kernel<<<256, 256, 0, stream>>>(x, mu0, rs0);
  h0_kernel<<<4096, 256, 0, stream>>>(x, style0, mu0, rs0, h0b);
  offset_mfma_kernel<<<1024, 256, 0, stream>>>(h0b, owtb, offb, off_t);
  deform_mfma_kernel<<<512, 512, 0, stream>>>(h0b, off_t, wtd, dcnb, tproj, h1b);
  gn1_stats_kernel<<<256, 256, 0, stream>>>(h1b, mu1, rs1);
  conv1_mfma_kernel<<<512, 512, 0, stream>>>(h1b, style1, mu1, rs1, wtc, c1b, x, out);
}

// Round 16
// 270.081 us; speedup vs baseline: 1.3301x; 1.0022x over previous
//
#include <hip/hip_runtime.h>
#include <hip/hip_bf16.h>

// ResnetBlockDDPMpp_Adagn: B=8, CIN=COUT=256, H=W=64, G=32, K=3
// Round 16: identical to R15 (broker container died before any measurement).
//  - R10/R12/R14 falsified occupancy/weight-traffic/LDS-size theories (all
//    flat ~102us). Mechanism (guide m97): __syncthreads == s_waitcnt
//    vmcnt(0) lgkmcnt(0) + s_barrier -> every per-tap barrier DRAINS the
//    prefetch loads; latency paid serially each tap; compiler therefore also
//    refuses to keep pre[] resident (VGPR 72).
//  - Fix (T4): k-loop barrier -> lgkmcnt(0)-only + raw s_barrier. LDS
//    ordering preserved; global prefetch stays in flight across barrier.

#define EPSV 1e-6f

typedef short  bf16x8 __attribute__((ext_vector_type(8)));
typedef float  f32x4  __attribute__((ext_vector_type(4)));

__device__ __forceinline__ float silu_f(float v){ return v / (1.f + __expf(-v)); }
__device__ __forceinline__ unsigned short f2bf(float f){
  unsigned int u = __float_as_uint(f);
  u = (u + 0x7FFFu + ((u >> 16) & 1u)) >> 16;
  return (unsigned short)u;
}
__device__ __forceinline__ float bf2f(unsigned short u){
  return __uint_as_float(((unsigned int)u) << 16);
}

// ---------------- ws layout (float units) ----------------
#define WS_H0B     0            // 8*4096*256 bf16
#define WS_H1B     4194304      // 8*4096*256 bf16
#define WS_OFFT    8388608      // 8*4096*27 fp32
#define WS_WTD     9273344      // dcn bf16 [9][32][256][8]
#define WS_WTC     9568256      // conv1 bf16 same
#define WS_OFFWTB  9863168      // offw bf16 [9][32][32][8]
#define WS_STYLE0  9900032
#define WS_STYLE1  9904128
#define WS_TPROJ   9908224
#define WS_MU0     9910272
#define WS_RS0     9910528
#define WS_MU1     9910784
#define WS_RS1     9911040
// end 9,911,296 floats = 39.6 MB

// ---------- prep: weight packs + tiny GEMMs ----------
__global__ __launch_bounds__(256) void prep_kernel(
    const float* __restrict__ zemb, const float* __restrict__ temb,
    const float* __restrict__ g0w, const float* __restrict__ g0b,
    const float* __restrict__ g1w, const float* __restrict__ g1b,
    const float* __restrict__ d0w, const float* __restrict__ d0b,
    const float* __restrict__ dcn_w, const float* __restrict__ c1w,
    const float* __restrict__ offw,
    unsigned short* __restrict__ wtd, unsigned short* __restrict__ wtc,
    unsigned short* __restrict__ offwtb,
    float* __restrict__ style0, float* __restrict__ style1, float* __restrict__ tproj)
{
  int blk = blockIdx.x, t = threadIdx.x;
  if (blk < 2304) {                       // dcn pack: e=((k*32+c8)*256+o)*8+j
    int e = blk*256 + t;
    int j = e & 7, o = (e >> 3) & 255, c8 = (e >> 11) & 31, k = e >> 16;
    wtd[e] = f2bf(dcn_w[((o*256 + c8*8 + j)*9) + k]);
  } else if (blk < 4608) {                // conv1 pack
    int e = (blk-2304)*256 + t;
    int j = e & 7, o = (e >> 3) & 255, c8 = (e >> 11) & 31, k = e >> 16;
    wtc[e] = f2bf(c1w[((o*256 + c8*8 + j)*9) + k]);
  } else if (blk < 4896) {                // offw pack: [9][32 c8][32 o][8 j], oc>=27 -> 0
    int e = (blk-4608)*256 + t;           // 73728 elems
    int j = e & 7, o = (e >> 3) & 31, c8 = (e >> 8) & 31, k = e >> 13;
    int c = c8*8 + j;
    offwtb[e] = (o < 27) ? f2bf(offw[((o*256 + c)*9) + k]) : (unsigned short)0;
  } else if (blk < 4912) {                // style0 = zemb @ g0w.T + g0b (8x512)
    int e = (blk-4896)*256 + t; int b = e >> 9, j = e & 511;
    float s = g0b[j];
    const float* z = zemb + b*256; const float* w = g0w + j*256;
    for (int i = 0; i < 256; ++i) s += z[i]*w[i];
    style0[e] = s;
  } else if (blk < 4928) {                // style1
    int e = (blk-4912)*256 + t; int b = e >> 9, j = e & 511;
    float s = g1b[j];
    const float* z = zemb + b*256; const float* w = g1w + j*256;
    for (int i = 0; i < 256; ++i) s += z[i]*w[i];
    style1[e] = s;
  } else {                                // tproj = silu(temb) @ d0w.T + d0b (8x256)
    int e = (blk-4928)*256 + t; int b = e >> 8, o = e & 255;
    float s = d0b[o];
    const float* tb = temb + b*512; const float* w = d0w + o*512;
    for (int i = 0; i < 512; ++i) s += silu_f(tb[i])*w[i];
    tproj[e] = s;
  }
}

// ---------- reductions ----------
__device__ __forceinline__ void block_reduce2(float& s, float& q){
  for (int off = 32; off > 0; off >>= 1) {
    s += __shfl_down(s, off, 64);
    q += __shfl_down(q, off, 64);
  }
  __shared__ float ss[4], qs[4];
  int wid = threadIdx.x >> 6, lane = threadIdx.x & 63;
  if (lane == 0) { ss[wid] = s; qs[wid] = q; }
  __syncthreads();
  if (threadIdx.x == 0) { s = ss[0]+ss[1]+ss[2]+ss[3]; q = qs[0]+qs[1]+qs[2]+qs[3]; }
}

__global__ __launch_bounds__(256) void gn0_stats_kernel(
    const float* __restrict__ x, float* __restrict__ mu, float* __restrict__ rs)
{
  int blk = blockIdx.x;  // b*32+g ; NCHW group = 32768 contiguous
  const float4* p4 = (const float4*)(x + (size_t)blk*32768);
  float s = 0.f, q = 0.f;
  for (int i = threadIdx.x; i < 8192; i += 256) {
    float4 v = p4[i];
    s += v.x+v.y+v.z+v.w;
    q += v.x*v.x + v.y*v.y + v.z*v.z + v.w*v.w;
  }
  block_reduce2(s, q);
  if (threadIdx.x == 0) {
    float m = s * (1.f/32768.f);
    float var = q * (1.f/32768.f) - m*m;
    mu[blk] = m; rs[blk] = rsqrtf(var + EPSV);
  }
}

// GN stats over h1b (bf16 NHWC)
__global__ __launch_bounds__(256) void gn1_stats_kernel(
    const unsigned short* __restrict__ h1b, float* __restrict__ mu, float* __restrict__ rs)
{
  int blk = blockIdx.x;  // b*32+g
  int b = blk >> 5, g = blk & 31;
  const unsigned short* base = h1b + (size_t)b*1048576 + g*8;
  float s = 0.f, q = 0.f;
  for (int px = threadIdx.x; px < 4096; px += 256) {
    bf16x8 v = *(const bf16x8*)(base + (size_t)px*256);
    #pragma unroll
    for (int e = 0; e < 8; ++e) {
      float f = bf2f((unsigned short)v[e]);
      s += f; q += f*f;
    }
  }
  block_reduce2(s, q);
  if (threadIdx.x == 0) {
    float m = s * (1.f/32768.f);
    float var = q * (1.f/32768.f) - m*m;
    mu[blk] = m; rs[blk] = rsqrtf(var + EPSV);
  }
}

// ---------- h0 = silu(adagn(x)) NCHW -> NHWC bf16 ----------
__global__ __launch_bounds__(256) void h0_kernel(
    const float* __restrict__ x, const float* __restrict__ style0,
    const float* __restrict__ mu, const float* __restrict__ rs,
    unsigned short* __restrict__ h0b)
{
  int blk = blockIdx.x;          // b(8) x ptile(64) x ctile(8)
  int b  = blk >> 9;
  int pt = (blk >> 3) & 63;
  int ct = blk & 7;
  __shared__ float tile[32][65];
  int p0 = pt*64, c0 = ct*32;
  int t = threadIdx.x;
  for (int it = 0; it < 8; ++it) {
    int c = c0 + it*4 + (t >> 6);
    int p = p0 + (t & 63);
    float v = x[((size_t)(b*256 + c))*4096 + p];
    int g = c >> 3;
    float m  = mu[b*32+g], r = rs[b*32+g];
    float ga = style0[b*512 + c], be = style0[b*512 + 256 + c];
    float u = ga * (v - m) * r + be;
    tile[c - c0][p - p0] = silu_f(u);
  }
  __syncthreads();
  for (int it = 0; it < 8; ++it) {
    int pp = it*8 + (t >> 5);
    int cc = t & 31;
    h0b[((size_t)(b*4096 + p0 + pp))*256 + c0 + cc] = f2bf(tile[cc][pp]);
  }
}

// ---------- offset conv MFMA: 32 px x 32 oc (27 used), K=2304 ----------
__global__ __launch_bounds__(256) void offset_mfma_kernel(
    const unsigned short* __restrict__ h0b, const unsigned short* __restrict__ wt,
    const float* __restrict__ off_b, float* __restrict__ off_t)
{
  int bid = blockIdx.x;
  int b  = bid & 7;                            // XCD swizzle
  int p0 = (bid >> 3) * 32;
  int y = p0 >> 6, xb = p0 & 63;
  int t = threadIdx.x;
  int lane = t & 63, wv = t >> 6;
  int r = lane & 15, g = lane >> 4;

  __shared__ unsigned short aw[3*34*264];      // rows y-1..y+1, px xb-1..xb+32

  const unsigned short* hbase = h0b + (size_t)b*1048576;
  for (int idx = t; idx < 3264; idx += 256) {
    int row = idx / 1088, rem = idx - row*1088;
    int px = rem >> 5, c8 = rem & 31;
    int yy = y + row - 1, xx = xb - 1 + px;
    bf16x8 v = {0,0,0,0,0,0,0,0};
    if (yy >= 0 && yy < 64 && xx >= 0 && xx < 64)
      v = *(const bf16x8*)&hbase[((size_t)yy*64 + xx)*256 + c8*8];
    *(bf16x8*)&aw[(row*34 + px)*264 + c8*8] = v;
  }
  __syncthreads();

  int m = wv & 1, n = wv >> 1;                 // wave -> (px half, oc half)
  f32x4 acc = {0.f,0.f,0.f,0.f};
  for (int k = 0; k < 9; ++k) {
    int ky = k/3, kxo = k%3;
    const unsigned short* abase = &aw[(ky*34)*264];
    const unsigned short* wk = wt + (size_t)k*8192;   // [32 c8][32 o][8]
    #pragma unroll
    for (int kc = 0; kc < 8; ++kc) {
      bf16x8 a = *(const bf16x8*)&abase[(kxo + m*16 + r)*264 + kc*32 + g*8];
      bf16x8 bf = *(const bf16x8*)&wk[(size_t)((kc*4 + g)*32 + n*16 + r)*8];
      acc = __builtin_amdgcn_mfma_f32_16x16x32_bf16(a, bf, acc, 0, 0, 0);
    }
  }

  int oc = n*16 + r;
  if (oc < 27) {
    float bs = off_b[oc];
    #pragma unroll
    for (int j = 0; j < 4; ++j) {
      int px = m*16 + g*4 + j;
      off_t[((size_t)(b*4096) + p0 + px)*27 + oc] = acc[j] + bs;
    }
  }
}

// ---------- deformable conv: dbuf, raw barrier (no vmcnt drain) ----------
__global__ __launch_bounds__(512, 2) void deform_mfma_kernel(
    const unsigned short* __restrict__ h0b, const float* __restrict__ off_t,
    const unsigned short* __restrict__ wt, const float* __restrict__ dcn_b,
    const float* __restrict__ tproj, unsigned short* __restrict__ h1b)
{
  int bid = blockIdx.x;
  int b  = bid & 7;                            // XCD swizzle (512 % 8 == 0)
  int p0 = (bid >> 3) * 64;                    // one full image row
  int t = threadIdx.x;                         // 0..511
  int lane = t & 63, wv = t >> 6;              // 8 waves
  int r = lane & 15, g = lane >> 4;

  __shared__ unsigned short samp[2][64*264];   // dbuf [px][264] bf16 (67.6KB)
  __shared__ int    pki[576];                  // packed iy0|ix0|iy1|ix1
  __shared__ float4 pkw[576];                  // w00..w11 -> total 79.1KB

  for (int tp = t; tp < 576; tp += 512) {      // 64 px x 9 taps
    int i = tp / 9, k = tp - i*9;
    int p = p0 + i; int y = p >> 6, xq = p & 63;
    const float* ob = off_t + ((size_t)(b*4096) + p)*27;
    float dy = ob[2*k], dx = ob[2*k+1];
    float mask = 1.f / (1.f + __expf(-ob[18+k]));
    float py = dy + (float)(k/3 + y - 1);
    float px = dx + (float)(k%3 + xq - 1);
    float fy0 = floorf(py), fx0 = floorf(px);
    float wy1 = py - fy0, wx1 = px - fx0;
    int y0 = (int)fy0, x0 = (int)fx0, y1 = y0+1, x1 = x0+1;
    float vy0 = (y0 >= 0 && y0 < 64) ? 1.f : 0.f;
    float vy1 = (y1 >= 0 && y1 < 64) ? 1.f : 0.f;
    float vx0 = (x0 >= 0 && x0 < 64) ? 1.f : 0.f;
    float vx1 = (x1 >= 0 && x1 < 64) ? 1.f : 0.f;
    int iy0 = min(max(y0,0),63), ix0 = min(max(x0,0),63);
    int iy1 = min(max(y1,0),63), ix1 = min(max(x1,0),63);
    pki[tp] = iy0 | (ix0 << 8) | (iy1 << 16) | (ix1 << 24);
    float4 w;
    w.x = (1.f-wy1)*(1.f-wx1)*vy0*vx0*mask;
    w.y = (1.f-wy1)*wx1      *vy0*vx1*mask;
    w.z = wy1      *(1.f-wx1)*vy1*vx0*mask;
    w.w = wy1      *wx1      *vy1*vx1*mask;
    pkw[tp] = w;
  }
  __syncthreads();

  f32x4 zero4 = {0.f,0.f,0.f,0.f};
  f32x4 acc[4][2];
  #pragma unroll
  for (int m = 0; m < 4; ++m) { acc[m][0] = zero4; acc[m][1] = zero4; }

  const unsigned short* hb = h0b + (size_t)b*1048576;
  int px = t >> 3;                             // 8 threads per pixel (64 px)
  int ci = (t & 7) * 32;                       // 32 contiguous channels each
  int o_base = wv*32 + r;                      // 8 waves x UNIQUE 32-out slice

  bf16x8 pre[16];                              // 4 corners x 32ch
  auto loadk = [&](int kk) {
    int tp = px*9 + kk;
    int pk = pki[tp];
    int iy0 = pk & 255, ix0 = (pk >> 8) & 255, iy1 = (pk >> 16) & 255, ix1 = (pk >> 24) & 255;
    const bf16x8* q00 = (const bf16x8*)(hb + ((size_t)iy0*64 + ix0)*256 + ci);
    const bf16x8* q01 = (const bf16x8*)(hb + ((size_t)iy0*64 + ix1)*256 + ci);
    const bf16x8* q10 = (const bf16x8*)(hb + ((size_t)iy1*64 + ix0)*256 + ci);
    const bf16x8* q11 = (const bf16x8*)(hb + ((size_t)iy1*64 + ix1)*256 + ci);
    pre[0] = q00[0]; pre[1] = q00[1]; pre[2] = q00[2]; pre[3] = q00[3];
    pre[4] = q01[0]; pre[5] = q01[1]; pre[6] = q01[2]; pre[7] = q01[3];
    pre[8] = q10[0]; pre[9] = q10[1]; pre[10] = q10[2]; pre[11] = q10[3];
    pre[12] = q11[0]; pre[13] = q11[1]; pre[14] = q11[2]; pre[15] = q11[3];
  };

  loadk(0);
  for (int k = 0; k < 9; ++k) {
    { // cvt + weighted sum from prefetch regs -> LDS buf k&1
      int tp = px*9 + k;
      float4 w = pkw[tp];
      unsigned short* sp = &samp[k & 1][px*264 + ci];
      #pragma unroll
      for (int ch = 0; ch < 4; ++ch) {
        bf16x8 o;
        #pragma unroll
        for (int e = 0; e < 8; ++e) {
          float v = w.x*bf2f((unsigned short)pre[ch][e])
                  + w.y*bf2f((unsigned short)pre[4+ch][e])
                  + w.z*bf2f((unsigned short)pre[8+ch][e])
                  + w.w*bf2f((unsigned short)pre[12+ch][e]);
          o[e] = (short)f2bf(v);
        }
        *(bf16x8*)(sp + ch*8) = o;
      }
    }
    if (k < 8) loadk(k+1);                     // prefetch stays in flight now
    // drain ONLY LDS ops, then raw barrier (no vmcnt(0) drain!)
    asm volatile("s_waitcnt lgkmcnt(0)" ::: "memory");
    __builtin_amdgcn_s_barrier();

    const unsigned short* sb = samp[k & 1];
    const unsigned short* wk = wt + (size_t)k*65536;   // [32][256][8] this tap
    #pragma unroll
    for (int kc = 0; kc < 8; ++kc) {
      bf16x8 a0 = *(const bf16x8*)&sb[(     r)*264 + kc*32 + g*8];
      bf16x8 a1 = *(const bf16x8*)&sb[(16 + r)*264 + kc*32 + g*8];
      bf16x8 a2 = *(const bf16x8*)&sb[(32 + r)*264 + kc*32 + g*8];
      bf16x8 a3 = *(const bf16x8*)&sb[(48 + r)*264 + kc*32 + g*8];
      const unsigned short* wb = wk + (size_t)(kc*4 + g)*2048 + o_base*8;
      bf16x8 b0 = *(const bf16x8*)&wb[  0*8];
      bf16x8 b1 = *(const bf16x8*)&wb[ 16*8];
      acc[0][0] = __builtin_amdgcn_mfma_f32_16x16x32_bf16(a0, b0, acc[0][0], 0, 0, 0);
      acc[0][1] = __builtin_amdgcn_mfma_f32_16x16x32_bf16(a0, b1, acc[0][1], 0, 0, 0);
      acc[1][0] = __builtin_amdgcn_mfma_f32_16x16x32_bf16(a1, b0, acc[1][0], 0, 0, 0);
      acc[1][1] = __builtin_amdgcn_mfma_f32_16x16x32_bf16(a1, b1, acc[1][1], 0, 0, 0);
      acc[2][0] = __builtin_amdgcn_mfma_f32_16x16x32_bf16(a2, b0, acc[2][0], 0, 0, 0);
      acc[2][1] = __builtin_amdgcn_mfma_f32_16x16x32_bf16(a2, b1, acc[2][1], 0, 0, 0);
      acc[3][0] = __builtin_amdgcn_mfma_f32_16x16x32_bf16(a3, b0, acc[3][0], 0, 0, 0);
      acc[3][1] = __builtin_amdgcn_mfma_f32_16x16x32_bf16(a3, b1, acc[3][1], 0, 0, 0);
    }
    // no second barrier: next tap writes the other buffer (WAR safe, see R9)
  }

  #pragma unroll
  for (int nn = 0; nn < 2; ++nn) {
    int o = o_base + nn*16;
    float bs = dcn_b[o] + tproj[b*256 + o];
    #pragma unroll
    for (int m = 0; m < 4; ++m)
      #pragma unroll
      for (int j = 0; j < 4; ++j) {
        int pxl = m*16 + g*4 + j;
        h1b[((size_t)(b*4096) + pxl + p0)*256 + o] = f2bf(acc[m][nn][j] + bs);
      }
  }
}

// ---------- conv1 3x3 MFMA + residual, adagn+silu fused into staging ----------
__global__ __launch_bounds__(512, 2) void conv1_mfma_kernel(
    const unsigned short* __restrict__ h1b, const float* __restrict__ style1,
    const float* __restrict__ mu, const float* __restrict__ rs,
    const unsigned short* __restrict__ wt,
    const float* __restrict__ c1_b, const float* __restrict__ x,
    float* __restrict__ out)
{
  int bid = blockIdx.x;
  int b  = bid & 7;                            // XCD swizzle (512 % 8 == 0)
  int p0 = (bid >> 3) * 64;                    // one full image row
  int y = p0 >> 6;
  int t = threadIdx.x;                         // 0..511
  int lane = t & 63, wv = t >> 6;              // 8 waves
  int r = lane & 15, g = lane >> 4;

  __shared__ unsigned short aw[3*66*264];      // rows y-1..y+1, px -1..64 (102KB)

  const unsigned short* h1base = h1b + (size_t)b*1048576;
  for (int idx = t; idx < 6336; idx += 512) {  // 3 rows * 66 px * 32 chunks(8c)
    int row = idx / 2112, rem = idx - row*2112;
    int px = rem >> 5, c8 = rem & 31;
    int yy = y + row - 1, xx = px - 1;
    bf16x8 v = {0,0,0,0,0,0,0,0};
    if (yy >= 0 && yy < 64 && xx >= 0 && xx < 64) {
      bf16x8 h = *(const bf16x8*)&h1base[((size_t)yy*64 + xx)*256 + c8*8];
      int gg = c8;                             // group = c8 (8 ch per group)
      float m  = mu[b*32+gg], rr = rs[b*32+gg];
      #pragma unroll
      for (int j = 0; j < 8; ++j) {
        int c = c8*8 + j;
        float ga = style1[b*512 + c], be = style1[b*512 + 256 + c];
        float u = ga * (bf2f((unsigned short)h[j]) - m) * rr + be;
        v[j] = (short)f2bf(silu_f(u));
      }
    }
    *(bf16x8*)&aw[(row*66 + px)*264 + c8*8] = v;
  }
  __syncthreads();

  f32x4 zero4 = {0.f,0.f,0.f,0.f};
  f32x4 acc[4][2];
  #pragma unroll
  for (int m = 0; m < 4; ++m) { acc[m][0] = zero4; acc[m][1] = zero4; }

  int o_base = wv*32 + r;                      // 8 waves x UNIQUE 32-out slice
  for (int k = 0; k < 9; ++k) {
    int ky = k/3, kxo = k%3;
    const unsigned short* abase = &aw[(ky*66)*264];
    const unsigned short* wk = wt + (size_t)k*65536;
    #pragma unroll
    for (int kc = 0; kc < 8; ++kc) {
      bf16x8 a0 = *(const bf16x8*)&abase[(kxo +      r)*264 + kc*32 + g*8];
      bf16x8 a1 = *(const bf16x8*)&abase[(kxo + 16 + r)*264 + kc*32 + g*8];
      bf16x8 a2 = *(const bf16x8*)&abase[(kxo + 32 + r)*264 + kc*32 + g*8];
      bf16x8 a3 = *(const bf16x8*)&abase[(kxo + 48 + r)*264 + kc*32 + g*8];
      const unsigned short* wb = wk + (size_t)(kc*4 + g)*2048 + o_base*8;
      bf16x8 b0 = *(const bf16x8*)&wb[  0*8];
      bf16x8 b1 = *(const bf16x8*)&wb[ 16*8];
      acc[0][0] = __builtin_amdgcn_mfma_f32_16x16x32_bf16(a0, b0, acc[0][0], 0, 0, 0);
      acc[0][1] = __builtin_amdgcn_mfma_f32_16x16x32_bf16(a0, b1, acc[0][1], 0, 0, 0);
      acc[1][0] = __builtin_amdgcn_mfma_f32_16x16x32_bf16(a1, b0, acc[1][0], 0, 0, 0);
      acc[1][1] = __builtin_amdgcn_mfma_f32_16x16x32_bf16(a1, b1, acc[1][1], 0, 0, 0);
      acc[2][0] = __builtin_amdgcn_mfma_f32_16x16x32_bf16(a2, b0, acc[2][0], 0, 0, 0);
      acc[2][1] = __builtin_amdgcn_mfma_f32_16x16x32_bf16(a2, b1, acc[2][1], 0, 0, 0);
      acc[3][0] = __builtin_amdgcn_mfma_f32_16x16x32_bf16(a3, b0, acc[3][0], 0, 0, 0);
      acc[3][1] = __builtin_amdgcn_mfma_f32_16x16x32_bf16(a3, b1, acc[3][1], 0, 0, 0);
    }
  }

  #pragma unroll
  for (int nn = 0; nn < 2; ++nn) {
    int o = o_base + nn*16;
    float cb = c1_b[o];
    #pragma unroll
    for (int m = 0; m < 4; ++m)
      #pragma unroll
      for (int j = 0; j < 4; ++j) {
        int pxl = m*16 + g*4 + j;
        size_t oi = ((size_t)(b*256 + o))*4096 + p0 + pxl;
        out[oi] = x[oi] + acc[m][nn][j] + cb;
      }
  }
}

extern "C" void kernel_launch(void* const* d_in, const int* in_sizes, int n_in,
                              void* d_out, int out_size, void* d_ws, size_t ws_size,
                              hipStream_t stream) {
  const float* x    = (const float*)d_in[0];
  const float* temb = (const float*)d_in[1];
  const float* zemb = (const float*)d_in[2];
  const float* g0w  = (const float*)d_in[3];
  const float* g0b  = (const float*)d_in[4];
  const float* offw = (const float*)d_in[5];
  const float* offb = (const float*)d_in[6];
  const float* dcnw = (const float*)d_in[7];
  const float* dcnb = (const float*)d_in[8];
  const float* d0w  = (const float*)d_in[9];
  const float* d0b  = (const float*)d_in[10];
  const float* g1w  = (const float*)d_in[11];
  const float* g1b  = (const float*)d_in[12];
  const float* c1w  = (const float*)d_in[13];
  const float* c1b  = (const float*)d_in[14];
  float* out = (float*)d_out;
  float* ws  = (float*)d_ws;

  unsigned short* h0b = (unsigned short*)(ws + WS_H0B);
  unsigned short* h1b = (unsigned short*)(ws + WS_H1B);
  float* off_t   = ws + WS_OFFT;
  unsigned short* wtd  = (unsigned short*)(ws + WS_WTD);
  unsigned short* wtc  = (unsigned short*)(ws + WS_WTC);
  unsigned short* owtb = (unsigned short*)(ws + WS_OFFWTB);
  float* style0  = ws + WS_STYLE0;
  float* style1  = ws + WS_STYLE1;
  float* tproj   = ws + WS_TPROJ;
  float* mu0     = ws + WS_MU0;
  float* rs0     = ws + WS_RS0;
  float* mu1     = ws + WS_MU1;
  float* rs1     = ws + WS_RS1;

  prep_kernel<<<4936, 256, 0, stream>>>(zemb, temb, g0w, g0b, g1w, g1b, d0w, d0b,
                                        dcnw, c1w, offw, wtd, wtc, owtb,
                                        style0, style1, tproj);
  gn0_stats_kernel<<<256, 256, 0, stream>>>(x, mu0, rs0);
  h0_kernel<<<4096, 256, 0, stream>>>(x, style0, mu0, rs0, h0b);
  offset_mfma_kernel<<<1024, 256, 0, stream>>>(h0b, owtb, offb, off_t);
  deform_mfma_kernel<<<512, 512, 0, stream>>>(h0b, off_t, wtd, dcnb, tproj, h1b);
  gn1_stats_kernel<<<256, 256, 0, stream>>>(h1b, mu1, rs1);
  conv1_mfma_kernel<<<512, 512, 0, stream>>>(h1b, style1, mu1, rs1, wtc, c1b, x, out);
}